// Round 1
// baseline (949.472 us; speedup 1.0000x reference)
//
#include <hip/hip_runtime.h>
#include <math.h>

// Problem constants (reference: BATCH=8, N_POINTS=2048, HOP=1)
#define NPTS    2048
#define NBINS   2049   // n+1 one-sided FFT bins (n_fft = 2n = 4096)
#define NFRAMES 2049   // frame centers 0..n
#define U       320    // truncated Gaussian support: u_c in [-160, 159]
#define PAD     160
#define FT      256    // frames per block
#define KT      8      // freq bins per block
#define FPT     8      // frames per thread

// --- prep: per-batch mean ---------------------------------------------------
__global__ void mean_kernel(const float* __restrict__ x, float* __restrict__ means) {
    __shared__ float red[256];
    const int b = blockIdx.x;
    float s = 0.f;
    for (int t = threadIdx.x; t < NPTS; t += 256) s += x[b * NPTS + t];
    red[threadIdx.x] = s;
    __syncthreads();
    for (int off = 128; off > 0; off >>= 1) {
        if (threadIdx.x < off) red[threadIdx.x] += red[threadIdx.x + off];
        __syncthreads();
    }
    if (threadIdx.x == 0) means[b] = red[0] * (1.f / (float)NPTS);
}

// --- main: truncated Gaussian-windowed correlation --------------------------
// power[b,k,f] = (sum_u xs[f+u]*g(u)*cos(pi*k*u/n))^2
//             + (sum_u xs[f+u]*g(u)*sin(pi*k*u/n))^2
// (the e^{-i pi k f / n} frame phase drops under |.|^2)
__global__ __launch_bounds__(256) void spec_kernel(
        const float* __restrict__ x, const float* __restrict__ lambd,
        const float* __restrict__ means, float* __restrict__ out) {
    __shared__ float xs[FT + U];  // 576 floats, span [f0-160, f0+255+160)

    const int b  = blockIdx.z;
    const int f0 = blockIdx.x * FT;
    const int k  = blockIdx.y * KT + (threadIdx.x & (KT - 1));
    const int fg = threadIdx.x >> 3;        // 0..31 frame-groups of 8
    const float mean = means[b];

    for (int j = threadIdx.x; j < FT + U; j += 256) {
        const int t = f0 + j - PAD;
        xs[j] = (t >= 0 && t < NPTS) ? (x[b * NPTS + t] - mean) : 0.f;
    }
    __syncthreads();

    const float sigma  = fabsf(lambd[0]);
    const float inv2s2 = 0.5f / (sigma * sigma);

    // rotation recurrence for e^{i * pi * k * u_c / n}, u_c = u - 160
    const float dphi = (float)M_PI * (float)k / (float)NPTS;
    float sn, cs, sd, cd;
    sincosf(-160.f * dphi, &sn, &cs);
    sincosf(dphi, &sd, &cd);

    // Gaussian double recurrence: g(u_c) = exp(-u_c^2 * inv2s2)
    float       g  = __expf(-(160.f * 160.f) * inv2s2); // g(-160)
    float       gr = __expf(319.f * inv2s2);            // g(u+1)/g(u) at u=-160
    const float gq = __expf(-2.f * inv2s2);             // ratio of ratios

    float accr[FPT], acci[FPT];
    #pragma unroll
    for (int j = 0; j < FPT; ++j) { accr[j] = 0.f; acci[j] = 0.f; }

    const int base = fg * FPT;
    float w[FPT];  // rolling window: w[j] = xs[base + u + j]
    #pragma unroll
    for (int j = 0; j < FPT; ++j) w[j] = xs[base + j];

    #pragma unroll 8
    for (int u = 0; u < U; ++u) {
        const float wc = g * cs;
        const float ws2 = g * sn;
        #pragma unroll
        for (int j = 0; j < FPT; ++j) {
            accr[j] = fmaf(w[j], wc, accr[j]);
            acci[j] = fmaf(w[j], ws2, acci[j]);
        }
        // shift rolling window (free after unroll: register renaming)
        #pragma unroll
        for (int j = 0; j < FPT - 1; ++j) w[j] = w[j + 1];
        w[FPT - 1] = xs[base + u + FPT];
        // rotate (cs, sn) by dphi
        const float cn = cs * cd - sn * sd;
        sn = fmaf(sn, cd, cs * sd);
        cs = cn;
        // advance Gaussian
        g  *= gr;
        gr *= gq;
    }

    if (k < NBINS) {
        float* orow = out + ((size_t)(b * NBINS + k)) * (size_t)NFRAMES;
        const int fbase = f0 + base;
        #pragma unroll
        for (int j = 0; j < FPT; ++j) {
            const int f = fbase + j;
            if (f < NFRAMES)
                orow[f] = fmaf(accr[j], accr[j], acci[j] * acci[j]);
        }
    }
}

extern "C" void kernel_launch(void* const* d_in, const int* in_sizes, int n_in,
                              void* d_out, int out_size, void* d_ws, size_t ws_size,
                              hipStream_t stream) {
    const float* x     = (const float*)d_in[0];
    const float* lambd = (const float*)d_in[1];
    float*       means = (float*)d_ws;   // 8 floats of scratch
    float*       out   = (float*)d_out;

    hipLaunchKernelGGL(mean_kernel, dim3(8), dim3(256), 0, stream, x, means);

    dim3 grid((NFRAMES + FT - 1) / FT,   // 9
              (NBINS + KT - 1) / KT,     // 257
              8);
    hipLaunchKernelGGL(spec_kernel, grid, dim3(256), 0, stream,
                       x, lambd, means, out);
}

// Round 2
// 190.882 us; speedup vs baseline: 4.9741x; 4.9741x over previous
//
#include <hip/hip_runtime.h>
#include <math.h>

// ---- problem constants -----------------------------------------------------
#define NPTS    2048
#define NBINS   2049            // k = 0..2048
#define NFRAMES 2049            // f = 0..2048
#define U       320             // truncated Gaussian support, u_c in [-160,159]
#define PAD     160
#define XPLEN   2560            // padded bf16 signal per batch (zeros outside)

// ---- GEMM tiling -----------------------------------------------------------
#define MTOT    4224            // interleaved re/im rows 2*2049=4098, padded to 33*128
#define MBLK    33
#define NBLK    17              // frames padded to 17*128 = 2176
#define BM      128
#define BN      128
#define SPAN    448             // BN + U
#define SSTRIDE 464             // span copy stride (els): 232 dwords == 8 mod 32
#define ASTRIDE 72              // A_lds row stride (els): keeps b128 16B-aligned

typedef __attribute__((ext_vector_type(8))) short short8_t;   // bf16x8 (4 VGPR)
typedef __attribute__((ext_vector_type(4))) short short4_t;   // bf16x4
typedef __attribute__((ext_vector_type(4))) float float4_t;   // fp32x4 acc

static __device__ __forceinline__ unsigned short f2bf(float f) {
    unsigned u = __float_as_uint(f);
    unsigned r = (u + 0x7fffu + ((u >> 16) & 1u)) >> 16;      // RNE
    return (unsigned short)r;
}

// ---- prep: per-batch mean --------------------------------------------------
__global__ void mean_kernel(const float* __restrict__ x, float* __restrict__ means) {
    __shared__ float red[256];
    const int b = blockIdx.x;
    float s = 0.f;
    for (int t = threadIdx.x; t < NPTS; t += 256) s += x[b * NPTS + t];
    red[threadIdx.x] = s;
    __syncthreads();
    for (int off = 128; off > 0; off >>= 1) {
        if (threadIdx.x < off) red[threadIdx.x] += red[threadIdx.x + off];
        __syncthreads();
    }
    if (threadIdx.x == 0) means[b] = red[0] * (1.f / (float)NPTS);
}

// ---- prep: padded bf16 signal xp[b][t] = xs_b[t-160] -----------------------
__global__ void xpgen_kernel(const float* __restrict__ x, const float* __restrict__ means,
                             unsigned short* __restrict__ xp) {
    const int idx = blockIdx.x * 256 + threadIdx.x;           // 8*2560
    const int b = idx / XPLEN;
    const int t = idx - b * XPLEN;
    float v = 0.f;
    const int s = t - PAD;
    if (s >= 0 && s < NPTS) v = x[b * NPTS + s] - means[b];
    xp[idx] = f2bf(v);
}

// ---- prep: W[m][u], m=2k+p (p=0 re / 1 im), bf16 ---------------------------
__global__ void wgen_kernel(const float* __restrict__ lambd, unsigned short* __restrict__ W) {
    const int idx = blockIdx.x * 256 + threadIdx.x;           // MTOT*U
    if (idx >= MTOT * U) return;
    const int m = idx / U;
    const int u = idx - m * U;
    const int k = m >> 1, p = m & 1;
    float val = 0.f;
    if (k < NBINS) {
        const float sigma = fabsf(lambd[0]);
        const float uc = (float)(u - PAD);
        const float g = __expf(-0.5f * uc * uc / (sigma * sigma));
        const float ph = (float)M_PI * (float)k * uc * (1.f / 2048.f);
        float sn, cs;
        sincosf(ph, &sn, &cs);
        val = g * (p ? sn : cs);
    }
    W[idx] = f2bf(val);
}

// ---- main: banded MFMA GEMM + power epilogue -------------------------------
// P[k,f] = (sum_u Wr[k,u] X[u,f])^2 + (sum_u Wi[k,u] X[u,f])^2, X[u,f]=xp[u+f]
__global__ __launch_bounds__(256) void spec_mfma(
        const unsigned short* __restrict__ W, const unsigned short* __restrict__ xp,
        float* __restrict__ out) {
    __shared__ unsigned short Alds[BM * ASTRIDE];   // 18432 B
    __shared__ unsigned short span[4 * SSTRIDE];    // 3712 B: 4 shift-copies

    const int tid = threadIdx.x;
    const int b  = blockIdx.z;
    const int n0 = blockIdx.x * BN;                 // frame origin
    const int m0 = blockIdx.y * BM;                 // interleaved-row origin

    // load span shift-copies: copy c holds xp[n0 + t + c], t in [0, SPAN)
    {
        const unsigned short* xpb = xp + b * XPLEN;
        for (int i = tid; i < 4 * SPAN; i += 256) {
            const int c = i / SPAN;
            const int t = i - c * SPAN;
            span[c * SSTRIDE + t] = xpb[n0 + t + c];
        }
    }

    const int lane = tid & 63;
    const int wv   = tid >> 6;
    const int wm   = (wv & 1) * 64;                 // wave 64x64 quadrant
    const int wn   = (wv >> 1) * 64;
    const int col  = lane & 15;
    const int q    = lane >> 4;

    float4_t acc[4][4];
    #pragma unroll
    for (int mt = 0; mt < 4; ++mt)
        #pragma unroll
        for (int nt = 0; nt < 4; ++nt)
            acc[mt][nt] = (float4_t){0.f, 0.f, 0.f, 0.f};

    // B-fragment base pointers (Hankel reads from shift-copies; 8B-aligned)
    const unsigned short* bptr[4];
    #pragma unroll
    for (int nt = 0; nt < 4; ++nt) {
        const int n = wn + nt * 16 + col;
        const int c = n & 3;
        bptr[nt] = span + c * SSTRIDE + (8 * q + n - c);
    }

    // A staging map: 2 threads per row, 32 els (64 B) each
    const int row  = tid >> 1;
    const int half = tid & 1;
    const unsigned short* wrow = W + (size_t)(m0 + row) * U + half * 32;
    float4* l4 = (float4*)(Alds + row * ASTRIDE + half * 32);

    #pragma unroll
    for (int s = 0; s < 5; ++s) {                   // K = 5 stages of BK=64
        const int kb = s * 64;
        const float4* g4 = (const float4*)(wrow + kb);
        float4 r0 = g4[0], r1 = g4[1], r2 = g4[2], r3 = g4[3];
        __syncthreads();                            // prev compute done (s0: span ready)
        l4[0] = r0; l4[1] = r1; l4[2] = r2; l4[3] = r3;
        __syncthreads();                            // A tile visible

        #pragma unroll
        for (int ks = 0; ks < 2; ++ks) {            // two k32 sub-steps
            const int kk = ks * 32;
            short8_t af[4], bf[4];
            #pragma unroll
            for (int mt = 0; mt < 4; ++mt)
                af[mt] = *(const short8_t*)(Alds + (wm + mt * 16 + col) * ASTRIDE + kk + q * 8);
            #pragma unroll
            for (int nt = 0; nt < 4; ++nt) {
                const unsigned short* p = bptr[nt] + kb + kk;
                short4_t lo = *(const short4_t*)(p);
                short4_t hi = *(const short4_t*)(p + 4);
                bf[nt] = __builtin_shufflevector(lo, hi, 0, 1, 2, 3, 4, 5, 6, 7);
            }
            #pragma unroll
            for (int mt = 0; mt < 4; ++mt)
                #pragma unroll
                for (int nt = 0; nt < 4; ++nt)
                    acc[mt][nt] = __builtin_amdgcn_mfma_f32_16x16x32_bf16(
                        af[mt], bf[nt], acc[mt][nt], 0, 0, 0);
        }
    }

    // epilogue: rows (q*4 + r): r=0,1 -> (re,im) of k; r=2,3 -> k+1
    const int fbase = n0 + wn + col;
    #pragma unroll
    for (int mt = 0; mt < 4; ++mt) {
        const int mrow = m0 + wm + mt * 16 + q * 4;   // even
        const int kk0  = mrow >> 1;
        #pragma unroll
        for (int nt = 0; nt < 4; ++nt) {
            const int f = fbase + nt * 16;
            if (f < NFRAMES) {
                const float4_t a = acc[mt][nt];
                const float p0 = a[0] * a[0] + a[1] * a[1];
                const float p1 = a[2] * a[2] + a[3] * a[3];
                if (kk0 < NBINS)
                    out[((size_t)b * NBINS + kk0) * NFRAMES + f] = p0;
                if (kk0 + 1 < NBINS)
                    out[((size_t)b * NBINS + kk0 + 1) * NFRAMES + f] = p1;
            }
        }
    }
}

// ---- launch ---------------------------------------------------------------
extern "C" void kernel_launch(void* const* d_in, const int* in_sizes, int n_in,
                              void* d_out, int out_size, void* d_ws, size_t ws_size,
                              hipStream_t stream) {
    const float* x     = (const float*)d_in[0];
    const float* lambd = (const float*)d_in[1];
    float*       out   = (float*)d_out;

    // ws layout: [0,32) means f32 | [256, 256+40960) xp bf16 | [41216, +2703360) W bf16
    char* ws = (char*)d_ws;
    float*          means = (float*)ws;
    unsigned short* xp    = (unsigned short*)(ws + 256);
    unsigned short* W     = (unsigned short*)(ws + 41216);

    hipLaunchKernelGGL(mean_kernel, dim3(8), dim3(256), 0, stream, x, means);
    hipLaunchKernelGGL(xpgen_kernel, dim3(8 * XPLEN / 256), dim3(256), 0, stream,
                       x, means, xp);
    hipLaunchKernelGGL(wgen_kernel, dim3((MTOT * U + 255) / 256), dim3(256), 0, stream,
                       lambd, W);

    dim3 grid(NBLK, MBLK, 8);   // (frames, rows, batch)
    hipLaunchKernelGGL(spec_mfma, grid, dim3(256), 0, stream, W, xp, out);
}

// Round 3
// 187.623 us; speedup vs baseline: 5.0605x; 1.0174x over previous
//
#include <hip/hip_runtime.h>
#include <math.h>

// ---- problem constants -----------------------------------------------------
#define NPTS    2048
#define NBINS   2049            // k = 0..2048
#define NFRAMES 2049            // f = 0..2048
#define U       320             // truncated Gaussian support, u_c in [-160,159]
#define PAD     160
#define XPLEN   2688            // padded bf16 signal per batch (zeros outside)

// ---- GEMM tiling -----------------------------------------------------------
#define MTOT    4224            // interleaved re/im rows 2*2049=4098, pad to 33*128
#define MBLK    33
#define NBLK    9               // frames padded to 9*256 = 2304
#define BM      128
#define BN      256
#define BK      64
#define SPAN    (BN + U)        // 576
#define SSTRIDE 592             // span copy stride (els): 296 dwords == 8 mod 32
#define ASTRIDE 72              // A_lds row stride (els): 16B-aligned, bank-staggered
#define ABUF    (BM * ASTRIDE)  // els per A buffer

typedef __attribute__((ext_vector_type(8))) short short8_t;   // bf16x8 (4 VGPR)
typedef __attribute__((ext_vector_type(4))) short short4_t;   // bf16x4
typedef __attribute__((ext_vector_type(4))) float float4_t;   // fp32x4 acc

static __device__ __forceinline__ unsigned short f2bf(float f) {
    unsigned u = __float_as_uint(f);
    unsigned r = (u + 0x7fffu + ((u >> 16) & 1u)) >> 16;      // RNE
    return (unsigned short)r;
}

// ---- prep 1: fused per-batch mean + padded bf16 signal ---------------------
__global__ void prep_kernel(const float* __restrict__ x, unsigned short* __restrict__ xp) {
    __shared__ float red[256];
    const int b = blockIdx.x;
    float s = 0.f;
    for (int t = threadIdx.x; t < NPTS; t += 256) s += x[b * NPTS + t];
    red[threadIdx.x] = s;
    __syncthreads();
    for (int off = 128; off > 0; off >>= 1) {
        if (threadIdx.x < off) red[threadIdx.x] += red[threadIdx.x + off];
        __syncthreads();
    }
    const float mean = red[0] * (1.f / (float)NPTS);
    for (int t = threadIdx.x; t < XPLEN; t += 256) {
        const int s2 = t - PAD;
        float v = (s2 >= 0 && s2 < NPTS) ? (x[b * NPTS + s2] - mean) : 0.f;
        xp[b * XPLEN + t] = f2bf(v);
    }
}

// ---- prep 2: W[m][u] via rotation + Gaussian recurrences -------------------
// m = 2k+p (p=0 re / 1 im); each thread fills one 64-u chunk of one row.
#define WCH 5                   // 320/64 chunks
__global__ void wgen_kernel(const float* __restrict__ lambd, unsigned short* __restrict__ W) {
    const int idx = blockIdx.x * 256 + threadIdx.x;
    if (idx >= MTOT * WCH) return;
    const int m  = idx / WCH;
    const int ch = idx - m * WCH;
    const int k = m >> 1, p = m & 1;
    unsigned int* wp = (unsigned int*)(W + (size_t)m * U + ch * 64);  // 2-el aligned
    if (k >= NBINS) {
        #pragma unroll
        for (int j = 0; j < 32; ++j) wp[j] = 0u;
        return;
    }
    const float sigma  = fabsf(lambd[0]);
    const float inv2s2 = 0.5f / (sigma * sigma);
    const float u0 = (float)(ch * 64 - PAD);                  // centered u at chunk start
    const float dphi = (float)M_PI * (float)k * (1.f / 2048.f);
    float sn, cs, sd, cd;
    sincosf(dphi * u0, &sn, &cs);
    sincosf(dphi, &sd, &cd);
    float       g  = __expf(-u0 * u0 * inv2s2);
    float       gr = __expf(-(2.f * u0 + 1.f) * inv2s2);
    const float gq = __expf(-2.f * inv2s2);
    #pragma unroll
    for (int j = 0; j < 32; ++j) {
        unsigned short lo = f2bf(g * (p ? sn : cs));
        float cn = cs * cd - sn * sd; sn = fmaf(sn, cd, cs * sd); cs = cn;
        g *= gr; gr *= gq;
        unsigned short hi = f2bf(g * (p ? sn : cs));
        cn = cs * cd - sn * sd; sn = fmaf(sn, cd, cs * sd); cs = cn;
        g *= gr; gr *= gq;
        wp[j] = (unsigned int)lo | ((unsigned int)hi << 16);
    }
}

// ---- main: banded MFMA GEMM + power epilogue -------------------------------
// P[k,f] = (sum_u Wr[k,u] X[u,f])^2 + (sum_u Wi[k,u] X[u,f])^2, X[u,f]=xp[u+f]
__global__ __launch_bounds__(256, 2) void spec_mfma(
        const unsigned short* __restrict__ W, const unsigned short* __restrict__ xp,
        float* __restrict__ out) {
    __shared__ unsigned short Alds[2 * ABUF];       // 36864 B double buffer
    __shared__ unsigned short span[4 * SSTRIDE];    // 4736 B: 4 shift-copies

    const int tid = threadIdx.x;
    const int b  = blockIdx.z;
    const int n0 = blockIdx.x * BN;                 // frame origin
    const int m0 = blockIdx.y * BM;                 // interleaved-row origin

    // span shift-copies: copy c holds xp[n0 + t + c], t in [0, SPAN)
    {
        const unsigned short* xpb = xp + b * XPLEN;
        for (int i = tid; i < 4 * SPAN; i += 256) {
            const int c = i / SPAN;
            const int t = i - c * SPAN;
            span[c * SSTRIDE + t] = xpb[n0 + t + c];
        }
    }

    const int lane = tid & 63;
    const int wv   = tid >> 6;
    const int wm   = (wv & 1) * 64;                 // wave M-quadrant
    const int wn   = (wv >> 1) * 128;               // wave N-half
    const int col  = lane & 15;
    const int q    = lane >> 4;

    // A staging map: 2 threads per row, 32 els (64 B) each
    const int row  = tid >> 1;
    const int half = tid & 1;
    const unsigned short* wrow = W + (size_t)(m0 + row) * U + half * 32;
    const int lbase = row * ASTRIDE + half * 32;

    // B Hankel base (lane-constant shift-copy: c = col&3 since wn, nt*16 == 0 mod 4)
    const int cc = col & 3;
    const unsigned short* bbase = span + cc * SSTRIDE + (wn + col - cc) + 8 * q;

    float4_t acc[4][8];
    #pragma unroll
    for (int mt = 0; mt < 4; ++mt)
        #pragma unroll
        for (int nt = 0; nt < 8; ++nt)
            acc[mt][nt] = (float4_t){0.f, 0.f, 0.f, 0.f};

    // prologue: stage 0 -> buf0, prefetch stage 1 into regs
    float4 r0, r1, r2, r3;
    {
        const float4* g4 = (const float4*)(wrow);
        r0 = g4[0]; r1 = g4[1]; r2 = g4[2]; r3 = g4[3];
        float4* l4 = (float4*)(Alds + lbase);
        l4[0] = r0; l4[1] = r1; l4[2] = r2; l4[3] = r3;
        const float4* g5 = (const float4*)(wrow + BK);
        r0 = g5[0]; r1 = g5[1]; r2 = g5[2]; r3 = g5[3];
    }
    __syncthreads();

    #pragma unroll
    for (int s = 0; s < 5; ++s) {
        if (s < 4) {   // write prefetched tile s+1 into the other buffer
            float4* l4 = (float4*)(Alds + ((s + 1) & 1) * ABUF + lbase);
            l4[0] = r0; l4[1] = r1; l4[2] = r2; l4[3] = r3;
        }
        if (s < 3) {   // prefetch tile s+2
            const float4* g4 = (const float4*)(wrow + (s + 2) * BK);
            r0 = g4[0]; r1 = g4[1]; r2 = g4[2]; r3 = g4[3];
        }
        const unsigned short* cur = Alds + (s & 1) * ABUF;
        const int kb = s * BK;
        #pragma unroll
        for (int ks = 0; ks < 2; ++ks) {
            const int kk = ks * 32;
            short8_t af[4], bf[8];
            #pragma unroll
            for (int mt = 0; mt < 4; ++mt)
                af[mt] = *(const short8_t*)(cur + (wm + mt * 16 + col) * ASTRIDE + kk + q * 8);
            #pragma unroll
            for (int nt = 0; nt < 8; ++nt) {
                const unsigned short* p = bbase + nt * 16 + kb + kk;
                short4_t lo = *(const short4_t*)(p);
                short4_t hi = *(const short4_t*)(p + 4);
                bf[nt] = __builtin_shufflevector(lo, hi, 0, 1, 2, 3, 4, 5, 6, 7);
            }
            #pragma unroll
            for (int mt = 0; mt < 4; ++mt)
                #pragma unroll
                for (int nt = 0; nt < 8; ++nt)
                    acc[mt][nt] = __builtin_amdgcn_mfma_f32_16x16x32_bf16(
                        af[mt], bf[nt], acc[mt][nt], 0, 0, 0);
        }
        __syncthreads();
    }

    // epilogue: acc rows (q*4 + r): r=0,1 -> (re,im) of k; r=2,3 -> k+1
    const int fbase = n0 + wn + col;
    #pragma unroll
    for (int mt = 0; mt < 4; ++mt) {
        const int mrow = m0 + wm + mt * 16 + q * 4;   // even
        const int kk0  = mrow >> 1;
        #pragma unroll
        for (int nt = 0; nt < 8; ++nt) {
            const int f = fbase + nt * 16;
            if (f < NFRAMES) {
                const float4_t a = acc[mt][nt];
                const float p0 = a[0] * a[0] + a[1] * a[1];
                const float p1 = a[2] * a[2] + a[3] * a[3];
                if (kk0 < NBINS)
                    out[((size_t)b * NBINS + kk0) * NFRAMES + f] = p0;
                if (kk0 + 1 < NBINS)
                    out[((size_t)b * NBINS + kk0 + 1) * NFRAMES + f] = p1;
            }
        }
    }
}

// ---- launch ---------------------------------------------------------------
extern "C" void kernel_launch(void* const* d_in, const int* in_sizes, int n_in,
                              void* d_out, int out_size, void* d_ws, size_t ws_size,
                              hipStream_t stream) {
    const float* x     = (const float*)d_in[0];
    const float* lambd = (const float*)d_in[1];
    float*       out   = (float*)d_out;

    // ws layout: [0, 43008) xp bf16 (8*2688) | [43264, +2703360) W bf16
    char* ws = (char*)d_ws;
    unsigned short* xp = (unsigned short*)ws;
    unsigned short* W  = (unsigned short*)(ws + 43264);

    hipLaunchKernelGGL(prep_kernel, dim3(8), dim3(256), 0, stream, x, xp);
    hipLaunchKernelGGL(wgen_kernel, dim3((MTOT * WCH + 255) / 256), dim3(256), 0, stream,
                       lambd, W);

    dim3 grid(NBLK, MBLK, 8);   // (frame-tiles, row-tiles, batch)
    hipLaunchKernelGGL(spec_mfma, grid, dim3(256), 0, stream, W, xp, out);
}